// Round 4
// baseline (213.582 us; speedup 1.0000x reference)
//
#include <hip/hip_runtime.h>
#include <math.h>

#define DDIM 256
#define HDIM 64
#define NTOK 1024
#define BDIM 256

typedef __attribute__((ext_vector_type(8))) short short8;
typedef __attribute__((ext_vector_type(4))) float f32x4;

__device__ __forceinline__ ushort f2bf(float f) {   // RNE f32 -> bf16 bits
    uint u = __float_as_uint(f);
    return (ushort)((u + 0x7FFF + ((u >> 16) & 1)) >> 16);
}
__device__ __forceinline__ float bf2f(ushort b) {
    return __uint_as_float(((uint)b) << 16);
}

// ---------------- k_pre: c12 + split-bf16 pack of G = gamma ⊙ W1 in MFMA B-fragment order.
// B-frag (16x16x32): lane l holds B[k = (l>>4)*8 + j][n = l&15], j=0..7, contiguous 16B.
// ghi/glo[e], e = ((kt*4+nt)*64 + lane)*8 + j.
__global__ void k_pre(const float* __restrict__ gamma, const float* __restrict__ beta,
                      const float* __restrict__ W1, const float* __restrict__ b1,
                      float* __restrict__ c12, ushort* __restrict__ ghi,
                      ushort* __restrict__ glo) {
    int tid = threadIdx.x;
    if (blockIdx.x == 0 && tid < HDIM) {
        float s1 = 0.f, s2 = 0.f;
        for (int d = 0; d < DDIM; ++d) {
            float w = W1[d * HDIM + tid];
            s1 = fmaf(gamma[d], w, s1);
            s2 = fmaf(beta[d],  w, s2);
        }
        c12[tid]        = s1;
        c12[HDIM + tid] = s2 + b1[tid];
    }
    int e = blockIdx.x * 256 + tid;            // 64 blocks x 256 = 16384 entries
    int j    = e & 7;
    int lane = (e >> 3) & 63;
    int nt   = (e >> 9) & 3;
    int kt   = e >> 11;
    int k = kt * 32 + (lane >> 4) * 8 + j;
    int n = nt * 16 + (lane & 15);
    float g = gamma[k] * W1[k * HDIM + n];
    ushort hi = f2bf(g);
    ushort lo = f2bf(g - bf2f(hi));
    ghi[e] = hi;
    glo[e] = lo;
}

// ---------------- k_mfma: fused LN-stats + bf16-split MFMA (xn@G) + GELU + W2 dot.
// 64 tokens/block, 256 threads (4 waves, 16 tokens each).
__global__ __launch_bounds__(256) void k_mfma(
    const float* __restrict__ x, const float* __restrict__ c12,
    const ushort* __restrict__ ghi, const ushort* __restrict__ glo,
    const float* __restrict__ W2, float* __restrict__ logits) {
    __shared__ ushort Ahi[64][256];
    __shared__ ushort Alo[64][256];
    __shared__ float smu[64], ssv[64];

    int tid = threadIdx.x, w = tid >> 6, lane = tid & 63;
    size_t tokbase = (size_t)blockIdx.x * 64;

    // ---- Phase A: coalesced load, fp32 stats, bf16 hi/lo split into swizzled LDS.
    for (int s = 0; s < 16; ++s) {
        int r = s * 4 + w;                              // this wave's row this step
        const float4* rp = reinterpret_cast<const float4*>(x + (tokbase + r) * DDIM);
        float4 v = rp[lane];                            // wave reads 1KB contiguous
        float s1 = (v.x + v.y) + (v.z + v.w);
        float s2 = fmaf(v.x, v.x, fmaf(v.y, v.y, fmaf(v.z, v.z, v.w * v.w)));
        #pragma unroll
        for (int off = 1; off < 64; off <<= 1) {
            s1 += __shfl_xor(s1, off);
            s2 += __shfl_xor(s2, off);
        }
        if (lane == 0) {
            float mu  = s1 * (1.f / DDIM);
            float var = fmaf(-mu, mu, s2 * (1.f / DDIM));
            smu[r] = mu;
            ssv[r] = rsqrtf(var + 1e-5f);
        }
        ushort h0 = f2bf(v.x), h1 = f2bf(v.y), h2 = f2bf(v.z), h3 = f2bf(v.w);
        ushort l0 = f2bf(v.x - bf2f(h0)), l1 = f2bf(v.y - bf2f(h1));
        ushort l2 = f2bf(v.z - bf2f(h2)), l3 = f2bf(v.w - bf2f(h3));
        int col = (lane * 4) ^ ((r & 7) << 3);          // XOR swizzle (16B units)
        uint2 ph, pl;
        ph.x = (uint)h0 | ((uint)h1 << 16); ph.y = (uint)h2 | ((uint)h3 << 16);
        pl.x = (uint)l0 | ((uint)l1 << 16); pl.y = (uint)l2 | ((uint)l3 << 16);
        *reinterpret_cast<uint2*>(&Ahi[r][col]) = ph;
        *reinterpret_cast<uint2*>(&Alo[r][col]) = pl;
    }
    __syncthreads();

    // ---- Phase B: C[64tok x 64h] = Xsplit @ Gsplit, wave w owns rows [w*16, w*16+16).
    const short8* gph = reinterpret_cast<const short8*>(ghi);
    const short8* gpl = reinterpret_cast<const short8*>(glo);
    int kgrp = lane >> 4;
    int arow = w * 16 + (lane & 15);
    int rx   = (arow & 7) << 3;

    f32x4 acc[4];
    #pragma unroll
    for (int nt = 0; nt < 4; ++nt) acc[nt] = (f32x4){0.f, 0.f, 0.f, 0.f};

    #pragma unroll
    for (int kt = 0; kt < 8; ++kt) {
        int col = (kt * 32 + kgrp * 8) ^ rx;
        short8 ah = *reinterpret_cast<const short8*>(&Ahi[arow][col]);
        short8 al = *reinterpret_cast<const short8*>(&Alo[arow][col]);
        #pragma unroll
        for (int nt = 0; nt < 4; ++nt) {
            short8 bh = gph[(kt * 4 + nt) * 64 + lane];
            short8 bl = gpl[(kt * 4 + nt) * 64 + lane];
            acc[nt] = __builtin_amdgcn_mfma_f32_16x16x32_bf16(ah, bh, acc[nt], 0, 0, 0);
            acc[nt] = __builtin_amdgcn_mfma_f32_16x16x32_bf16(al, bh, acc[nt], 0, 0, 0);
            acc[nt] = __builtin_amdgcn_mfma_f32_16x16x32_bf16(ah, bl, acc[nt], 0, 0, 0);
        }
    }

    // ---- Epilogue: pre = sv*(a - mu*c1) + c2; GELU(exact); dot W2; 16-lane reduce.
    // C layout: lane holds (token m = kgrp*4 + r, h = nt*16 + (lane&15)).
    int c = lane & 15;
    float c1v[4], c2v[4], w2v[4];
    #pragma unroll
    for (int nt = 0; nt < 4; ++nt) {
        c1v[nt] = c12[nt * 16 + c];
        c2v[nt] = c12[HDIM + nt * 16 + c];
        w2v[nt] = W2[nt * 16 + c];
    }
    #pragma unroll
    for (int r = 0; r < 4; ++r) {
        int m  = kgrp * 4 + r;
        float mu = smu[w * 16 + m];
        float sv = ssv[w * 16 + m];
        float v = 0.f;
        #pragma unroll
        for (int nt = 0; nt < 4; ++nt) {
            float pre = fmaf(sv, fmaf(-mu, c1v[nt], acc[nt][r]), c2v[nt]);
            float g   = 0.5f * pre * (1.f + erff(pre * 0.70710678118654752f));
            v = fmaf(g, w2v[nt], v);
        }
        #pragma unroll
        for (int off = 1; off < 16; off <<= 1) v += __shfl_xor(v, off);
        if (c == 0) logits[tokbase + w * 16 + m] = v;
    }
}

// ---------------- Fallback VALU logits kernel (R3 path) if ws too small for packs.
__global__ __launch_bounds__(256) void k_logits(
    const float* __restrict__ x, const float* __restrict__ gamma,
    const float* __restrict__ W1, const float* __restrict__ W2,
    const float* __restrict__ c12, float* __restrict__ logits) {
    __shared__ float plog[128];
    int half = __builtin_amdgcn_readfirstlane(threadIdx.x >> 7);
    int tl   = threadIdx.x & 127;
    size_t t = (size_t)blockIdx.x * 128 + tl;
    const float4* row = reinterpret_cast<const float4*>(x + t * DDIM);
    const float* Wh   = W1 + half * 32;

    float acc[32];
    #pragma unroll
    for (int h = 0; h < 32; ++h) acc[h] = 0.f;
    float sum = 0.f, sq = 0.f;
    for (int i = 0; i < DDIM / 4; ++i) {
        float4 v = row[i];
        sum += (v.x + v.y) + (v.z + v.w);
        sq = fmaf(v.x, v.x, sq); sq = fmaf(v.y, v.y, sq);
        sq = fmaf(v.z, v.z, sq); sq = fmaf(v.w, v.w, sq);
        float xs[4] = {v.x, v.y, v.z, v.w};
        #pragma unroll
        for (int j = 0; j < 4; ++j) {
            int d = i * 4 + j;
            float xg = xs[j] * gamma[d];
            #pragma unroll
            for (int h = 0; h < 32; ++h)
                acc[h] = fmaf(xg, Wh[d * HDIM + h], acc[h]);
        }
    }
    float mu   = sum * (1.f / DDIM);
    float var  = fmaf(-mu, mu, sq * (1.f / DDIM));
    float sinv = rsqrtf(var + 1e-5f);
    float pl = 0.f;
    #pragma unroll
    for (int h = 0; h < 32; ++h) {
        int hg = half * 32 + h;
        float pre = fmaf(sinv, fmaf(-mu, c12[hg], acc[h]), c12[HDIM + hg]);
        float g   = 0.5f * pre * (1.f + erff(pre * 0.70710678118654752f));
        pl = fmaf(g, W2[hg], pl);
    }
    if (half) plog[tl] = pl;
    __syncthreads();
    if (!half) logits[t] = pl + plog[tl];
}

// ---------------- k_softmax: one block per b, in-place logits -> weights.
__global__ __launch_bounds__(256) void k_softmax(float* __restrict__ wts) {
    __shared__ float smax[4], ssum[4];
    int b = blockIdx.x;
    float* row = wts + (size_t)b * NTOK;
    int w = threadIdx.x >> 6, lane = threadIdx.x & 63;

    float v[4];
    float m = -1e30f;
    #pragma unroll
    for (int k = 0; k < 4; ++k) { v[k] = row[threadIdx.x + 256 * k]; m = fmaxf(m, v[k]); }
    #pragma unroll
    for (int off = 32; off; off >>= 1) m = fmaxf(m, __shfl_xor(m, off));
    if (lane == 0) smax[w] = m;
    __syncthreads();
    m = fmaxf(fmaxf(smax[0], smax[1]), fmaxf(smax[2], smax[3]));

    float s = 0.f;
    #pragma unroll
    for (int k = 0; k < 4; ++k) { v[k] = __expf(v[k] - m); s += v[k]; }
    #pragma unroll
    for (int off = 32; off; off >>= 1) s += __shfl_xor(s, off);
    if (lane == 0) ssum[w] = s;
    __syncthreads();
    s = (ssum[0] + ssum[1]) + (ssum[2] + ssum[3]);
    float inv = 1.f / s;
    #pragma unroll
    for (int k = 0; k < 4; ++k) row[threadIdx.x + 256 * k] = v[k] * inv;
}

// ---------------- k_partial: summary partials over n-splits.
__global__ __launch_bounds__(256) void k_partial(const float* __restrict__ x,
                                                 const float* __restrict__ wts,
                                                 float* __restrict__ part, int rows) {
    int b = blockIdx.y, s = blockIdx.x, d = threadIdx.x;
    int n0 = s * rows;
    const float* w  = wts + (size_t)b * NTOK + n0;
    const float* xp = x + ((size_t)b * NTOK + n0) * DDIM + d;

    float a0 = 0.f, a1 = 0.f, a2 = 0.f, a3 = 0.f, a4 = 0.f, a5 = 0.f, a6 = 0.f, a7 = 0.f;
    for (int n = 0; n < rows; n += 8) {
        a0 = fmaf(w[n + 0], xp[(size_t)(n + 0) * DDIM], a0);
        a1 = fmaf(w[n + 1], xp[(size_t)(n + 1) * DDIM], a1);
        a2 = fmaf(w[n + 2], xp[(size_t)(n + 2) * DDIM], a2);
        a3 = fmaf(w[n + 3], xp[(size_t)(n + 3) * DDIM], a3);
        a4 = fmaf(w[n + 4], xp[(size_t)(n + 4) * DDIM], a4);
        a5 = fmaf(w[n + 5], xp[(size_t)(n + 5) * DDIM], a5);
        a6 = fmaf(w[n + 6], xp[(size_t)(n + 6) * DDIM], a6);
        a7 = fmaf(w[n + 7], xp[(size_t)(n + 7) * DDIM], a7);
    }
    float acc = ((a0 + a1) + (a2 + a3)) + ((a4 + a5) + (a6 + a7));
    part[((size_t)(b * gridDim.x + s)) * DDIM + d] = acc;
}

// ---------------- k_reduce: summary[b,d] = sum_s part[b,s,d]
__global__ __launch_bounds__(256) void k_reduce(const float* __restrict__ part,
                                                float* __restrict__ out, int nsplit) {
    int i = blockIdx.x * 256 + threadIdx.x;
    int b = i >> 8, d = i & 255;
    float s = 0.f;
    for (int k = 0; k < nsplit; ++k) s += part[((size_t)(b * nsplit + k)) * DDIM + d];
    out[i] = s;
}

extern "C" void kernel_launch(void* const* d_in, const int* in_sizes, int n_in,
                              void* d_out, int out_size, void* d_ws, size_t ws_size,
                              hipStream_t stream) {
    const float* x     = (const float*)d_in[0];
    const float* gamma = (const float*)d_in[1];
    const float* beta  = (const float*)d_in[2];
    const float* W1    = (const float*)d_in[3];
    const float* b1    = (const float*)d_in[4];
    const float* W2    = (const float*)d_in[5];
    // d_in[6] = b2: softmax-invariant, unused.

    float* out     = (float*)d_out;
    float* summary = out;                       // B*D
    float* wts     = out + (size_t)BDIM * DDIM; // B*N (logits staged, then weights)

    // ws layout: c12 (512B) | ghi (32KB) | glo (32KB) | part (2MB)
    float*  c12 = (float*)d_ws;
    ushort* ghi = (ushort*)((char*)d_ws + 512);
    ushort* glo = ghi + 16384;
    float*  part = (float*)((char*)d_ws + 512 + 65536);
    size_t need_pack = 512 + 65536;

    const int NSPLIT = 8;
    size_t need_split = need_pack + (size_t)NSPLIT * BDIM * DDIM * sizeof(float);
    bool use_mfma = (ws_size >= need_pack);
    bool split    = (ws_size >= need_split);

    if (use_mfma) {
        hipLaunchKernelGGL(k_pre, dim3(64), dim3(256), 0, stream,
                           gamma, beta, W1, b1, c12, ghi, glo);
        hipLaunchKernelGGL(k_mfma, dim3(BDIM * NTOK / 64), dim3(256), 0, stream,
                           x, c12, ghi, glo, W2, wts);
    } else {
        // need at least 512B for c12; ws smaller than that is not expected.
        hipLaunchKernelGGL(k_pre, dim3(1), dim3(256), 0, stream,
                           gamma, beta, W1, b1, c12, ghi, glo);
        hipLaunchKernelGGL(k_logits, dim3(BDIM * NTOK / 128), dim3(256), 0, stream,
                           x, gamma, W1, W2, c12, wts);
    }
    hipLaunchKernelGGL(k_softmax, dim3(BDIM), dim3(256), 0, stream, wts);
    if (split) {
        hipLaunchKernelGGL(k_partial, dim3(NSPLIT, BDIM), dim3(256), 0, stream,
                           x, wts, part, NTOK / NSPLIT);
        hipLaunchKernelGGL(k_reduce, dim3(BDIM * DDIM / 256), dim3(256), 0, stream,
                           part, summary, NSPLIT);
    } else {
        hipLaunchKernelGGL(k_partial, dim3(1, BDIM), dim3(256), 0, stream,
                           x, wts, summary, NTOK);
    }
}

// Round 5
// 142.307 us; speedup vs baseline: 1.5009x; 1.5009x over previous
//
#include <hip/hip_runtime.h>
#include <math.h>

#define DDIM 256
#define HDIM 64
#define NTOK 1024
#define BDIM 256

typedef __attribute__((ext_vector_type(8))) short short8;
typedef __attribute__((ext_vector_type(4))) float f32x4;

__device__ __forceinline__ ushort f2bf(float f) {   // RNE f32 -> bf16 bits
    uint u = __float_as_uint(f);
    return (ushort)((u + 0x7FFF + ((u >> 16) & 1)) >> 16);
}
__device__ __forceinline__ float bf2f(ushort b) {
    return __uint_as_float(((uint)b) << 16);
}

// ---------------- k_pre: c12 + split-bf16 pack of G = gamma ⊙ W1 in MFMA B-fragment order.
// B-frag (16x16x32): lane l holds B[k = (l>>4)*8 + j][n = l&15], j=0..7, contiguous 16B.
// ghi/glo[e], e = ((kt*4+nt)*64 + lane)*8 + j.   (validated in R4)
__global__ void k_pre(const float* __restrict__ gamma, const float* __restrict__ beta,
                      const float* __restrict__ W1, const float* __restrict__ b1,
                      float* __restrict__ c12, ushort* __restrict__ ghi,
                      ushort* __restrict__ glo) {
    int tid = threadIdx.x;
    if (blockIdx.x == 0 && tid < HDIM) {
        float s1 = 0.f, s2 = 0.f;
        for (int d = 0; d < DDIM; ++d) {
            float w = W1[d * HDIM + tid];
            s1 = fmaf(gamma[d], w, s1);
            s2 = fmaf(beta[d],  w, s2);
        }
        c12[tid]        = s1;
        c12[HDIM + tid] = s2 + b1[tid];
    }
    int e = blockIdx.x * 256 + tid;            // 64 blocks x 256 = 16384 entries
    int j    = e & 7;
    int lane = (e >> 3) & 63;
    int nt   = (e >> 9) & 3;
    int kt   = e >> 11;
    int k = kt * 32 + (lane >> 4) * 8 + j;
    int n = nt * 16 + (lane & 15);
    float g = gamma[k] * W1[k * HDIM + n];
    ushort hi = f2bf(g);
    ushort lo = f2bf(g - bf2f(hi));
    ghi[e] = hi;
    glo[e] = lo;
}

// ---------------- k_mfma v2: LDS-free fused LN-stats + split-bf16 MFMA + GELU + W2 dot.
// 4 independent waves/block, 16 tokens/wave. A-fragments loaded straight from global
// in frag order (per kt: 16 rows x 128B, fully consumed); stats in-loop; no barriers.
__global__ __launch_bounds__(256) void k_mfma(
    const float* __restrict__ x, const float* __restrict__ c12,
    const ushort* __restrict__ ghi, const ushort* __restrict__ glo,
    const float* __restrict__ W2, float* __restrict__ logits) {
    int tid = threadIdx.x, w = tid >> 6, lane = tid & 63;
    int m = lane & 15, kg = lane >> 4;
    size_t tok0 = (size_t)blockIdx.x * 64 + (size_t)w * 16;   // this wave's 16 tokens

    const float4*  rp  = reinterpret_cast<const float4*>(x + (tok0 + m) * DDIM + kg * 8);
    const short8*  gph = reinterpret_cast<const short8*>(ghi);
    const short8*  gpl = reinterpret_cast<const short8*>(glo);

    f32x4 acc[4];
    #pragma unroll
    for (int nt = 0; nt < 4; ++nt) acc[nt] = (f32x4){0.f, 0.f, 0.f, 0.f};

    float s1 = 0.f, s2 = 0.f;

    #pragma unroll
    for (int kt = 0; kt < 8; ++kt) {
        float4 xa = rp[kt * 8];        // k = kt*32 + kg*8 + {0..3}
        float4 xb = rp[kt * 8 + 1];    // k = kt*32 + kg*8 + {4..7}

        s1 += ((xa.x + xa.y) + (xa.z + xa.w)) + ((xb.x + xb.y) + (xb.z + xb.w));
        s2 = fmaf(xa.x, xa.x, s2); s2 = fmaf(xa.y, xa.y, s2);
        s2 = fmaf(xa.z, xa.z, s2); s2 = fmaf(xa.w, xa.w, s2);
        s2 = fmaf(xb.x, xb.x, s2); s2 = fmaf(xb.y, xb.y, s2);
        s2 = fmaf(xb.z, xb.z, s2); s2 = fmaf(xb.w, xb.w, s2);

        uint u0 = __float_as_uint(xa.x), u1 = __float_as_uint(xa.y);
        uint u2 = __float_as_uint(xa.z), u3 = __float_as_uint(xa.w);
        uint u4 = __float_as_uint(xb.x), u5 = __float_as_uint(xb.y);
        uint u6 = __float_as_uint(xb.z), u7 = __float_as_uint(xb.w);

        union { uint4 u; short8 s; } Ah, Al;
        // hi = RTZ bf16 (top 16 bits)
        Ah.u.x = (u0 >> 16) | (u1 & 0xFFFF0000u);
        Ah.u.y = (u2 >> 16) | (u3 & 0xFFFF0000u);
        Ah.u.z = (u4 >> 16) | (u5 & 0xFFFF0000u);
        Ah.u.w = (u6 >> 16) | (u7 & 0xFFFF0000u);
        // lo = RTZ bf16 of exact residual (x - hi)
        uint r0 = __float_as_uint(xa.x - __uint_as_float(u0 & 0xFFFF0000u));
        uint r1 = __float_as_uint(xa.y - __uint_as_float(u1 & 0xFFFF0000u));
        uint r2 = __float_as_uint(xa.z - __uint_as_float(u2 & 0xFFFF0000u));
        uint r3 = __float_as_uint(xa.w - __uint_as_float(u3 & 0xFFFF0000u));
        uint r4 = __float_as_uint(xb.x - __uint_as_float(u4 & 0xFFFF0000u));
        uint r5 = __float_as_uint(xb.y - __uint_as_float(u5 & 0xFFFF0000u));
        uint r6 = __float_as_uint(xb.z - __uint_as_float(u6 & 0xFFFF0000u));
        uint r7 = __float_as_uint(xb.w - __uint_as_float(u7 & 0xFFFF0000u));
        Al.u.x = (r0 >> 16) | (r1 & 0xFFFF0000u);
        Al.u.y = (r2 >> 16) | (r3 & 0xFFFF0000u);
        Al.u.z = (r4 >> 16) | (r5 & 0xFFFF0000u);
        Al.u.w = (r6 >> 16) | (r7 & 0xFFFF0000u);

        #pragma unroll
        for (int nt = 0; nt < 4; ++nt) {
            short8 bh = gph[(kt * 4 + nt) * 64 + lane];
            short8 bl = gpl[(kt * 4 + nt) * 64 + lane];
            acc[nt] = __builtin_amdgcn_mfma_f32_16x16x32_bf16(Ah.s, bh, acc[nt], 0, 0, 0);
            acc[nt] = __builtin_amdgcn_mfma_f32_16x16x32_bf16(Al.s, bh, acc[nt], 0, 0, 0);
            acc[nt] = __builtin_amdgcn_mfma_f32_16x16x32_bf16(Ah.s, bl, acc[nt], 0, 0, 0);
        }
    }

    // Exact fp32 row stats: lane covered k = kg*8+{0..7} (+32kt) of row m -> union over
    // the 4 kg-groups is the full row. Reduce across kg via xor 16, 32.
    s1 += __shfl_xor(s1, 16); s1 += __shfl_xor(s1, 32);
    s2 += __shfl_xor(s2, 16); s2 += __shfl_xor(s2, 32);
    float mu  = s1 * (1.f / DDIM);                    // stats for row m (= lane&15)
    float var = fmaf(-mu, mu, s2 * (1.f / DDIM));
    float sv  = rsqrtf(var + 1e-5f);

    // Epilogue. C layout: acc[nt][r] = C[row = kg*4 + r][h = nt*16 + m].
    float c1v[4], c2v[4], w2v[4];
    #pragma unroll
    for (int nt = 0; nt < 4; ++nt) {
        c1v[nt] = c12[nt * 16 + m];
        c2v[nt] = c12[HDIM + nt * 16 + m];
        w2v[nt] = W2[nt * 16 + m];
    }
    #pragma unroll
    for (int r = 0; r < 4; ++r) {
        int row = kg * 4 + r;
        float mur = __shfl(mu, row);    // stats for row live in lanes with (lane&15)==row
        float svr = __shfl(sv, row);
        float v = 0.f;
        #pragma unroll
        for (int nt = 0; nt < 4; ++nt) {
            float pre = fmaf(svr, fmaf(-mur, c1v[nt], acc[nt][r]), c2v[nt]);
            float g   = 0.5f * pre * (1.f + erff(pre * 0.70710678118654752f));
            v = fmaf(g, w2v[nt], v);
        }
        v += __shfl_xor(v, 1); v += __shfl_xor(v, 2);
        v += __shfl_xor(v, 4); v += __shfl_xor(v, 8);
        if (m == 0) logits[tok0 + row] = v;
    }
}

// ---------------- Fallback VALU logits kernel (R3 path) if ws too small for packs.
__global__ __launch_bounds__(256) void k_logits(
    const float* __restrict__ x, const float* __restrict__ gamma,
    const float* __restrict__ W1, const float* __restrict__ W2,
    const float* __restrict__ c12, float* __restrict__ logits) {
    __shared__ float plog[128];
    int half = __builtin_amdgcn_readfirstlane(threadIdx.x >> 7);
    int tl   = threadIdx.x & 127;
    size_t t = (size_t)blockIdx.x * 128 + tl;
    const float4* row = reinterpret_cast<const float4*>(x + t * DDIM);
    const float* Wh   = W1 + half * 32;

    float acc[32];
    #pragma unroll
    for (int h = 0; h < 32; ++h) acc[h] = 0.f;
    float sum = 0.f, sq = 0.f;
    for (int i = 0; i < DDIM / 4; ++i) {
        float4 v = row[i];
        sum += (v.x + v.y) + (v.z + v.w);
        sq = fmaf(v.x, v.x, sq); sq = fmaf(v.y, v.y, sq);
        sq = fmaf(v.z, v.z, sq); sq = fmaf(v.w, v.w, sq);
        float xs[4] = {v.x, v.y, v.z, v.w};
        #pragma unroll
        for (int j = 0; j < 4; ++j) {
            int d = i * 4 + j;
            float xg = xs[j] * gamma[d];
            #pragma unroll
            for (int h = 0; h < 32; ++h)
                acc[h] = fmaf(xg, Wh[d * HDIM + h], acc[h]);
        }
    }
    float mu   = sum * (1.f / DDIM);
    float var  = fmaf(-mu, mu, sq * (1.f / DDIM));
    float sinv = rsqrtf(var + 1e-5f);
    float pl = 0.f;
    #pragma unroll
    for (int h = 0; h < 32; ++h) {
        int hg = half * 32 + h;
        float pre = fmaf(sinv, fmaf(-mu, c12[hg], acc[h]), c12[HDIM + hg]);
        float g   = 0.5f * pre * (1.f + erff(pre * 0.70710678118654752f));
        pl = fmaf(g, W2[hg], pl);
    }
    if (half) plog[tl] = pl;
    __syncthreads();
    if (!half) logits[t] = pl + plog[tl];
}

// ---------------- k_softmax: one block per b, in-place logits -> weights.
__global__ __launch_bounds__(256) void k_softmax(float* __restrict__ wts) {
    __shared__ float smax[4], ssum[4];
    int b = blockIdx.x;
    float* row = wts + (size_t)b * NTOK;
    int w = threadIdx.x >> 6, lane = threadIdx.x & 63;

    float v[4];
    float m = -1e30f;
    #pragma unroll
    for (int k = 0; k < 4; ++k) { v[k] = row[threadIdx.x + 256 * k]; m = fmaxf(m, v[k]); }
    #pragma unroll
    for (int off = 32; off; off >>= 1) m = fmaxf(m, __shfl_xor(m, off));
    if (lane == 0) smax[w] = m;
    __syncthreads();
    m = fmaxf(fmaxf(smax[0], smax[1]), fmaxf(smax[2], smax[3]));

    float s = 0.f;
    #pragma unroll
    for (int k = 0; k < 4; ++k) { v[k] = __expf(v[k] - m); s += v[k]; }
    #pragma unroll
    for (int off = 32; off; off >>= 1) s += __shfl_xor(s, off);
    if (lane == 0) ssum[w] = s;
    __syncthreads();
    s = (ssum[0] + ssum[1]) + (ssum[2] + ssum[3]);
    float inv = 1.f / s;
    #pragma unroll
    for (int k = 0; k < 4; ++k) row[threadIdx.x + 256 * k] = v[k] * inv;
}

// ---------------- k_partial: summary partials over n-splits.
__global__ __launch_bounds__(256) void k_partial(const float* __restrict__ x,
                                                 const float* __restrict__ wts,
                                                 float* __restrict__ part, int rows) {
    int b = blockIdx.y, s = blockIdx.x, d = threadIdx.x;
    int n0 = s * rows;
    const float* w  = wts + (size_t)b * NTOK + n0;
    const float* xp = x + ((size_t)b * NTOK + n0) * DDIM + d;

    float a0 = 0.f, a1 = 0.f, a2 = 0.f, a3 = 0.f, a4 = 0.f, a5 = 0.f, a6 = 0.f, a7 = 0.f;
    for (int n = 0; n < rows; n += 8) {
        a0 = fmaf(w[n + 0], xp[(size_t)(n + 0) * DDIM], a0);
        a1 = fmaf(w[n + 1], xp[(size_t)(n + 1) * DDIM], a1);
        a2 = fmaf(w[n + 2], xp[(size_t)(n + 2) * DDIM], a2);
        a3 = fmaf(w[n + 3], xp[(size_t)(n + 3) * DDIM], a3);
        a4 = fmaf(w[n + 4], xp[(size_t)(n + 4) * DDIM], a4);
        a5 = fmaf(w[n + 5], xp[(size_t)(n + 5) * DDIM], a5);
        a6 = fmaf(w[n + 6], xp[(size_t)(n + 6) * DDIM], a6);
        a7 = fmaf(w[n + 7], xp[(size_t)(n + 7) * DDIM], a7);
    }
    float acc = ((a0 + a1) + (a2 + a3)) + ((a4 + a5) + (a6 + a7));
    part[((size_t)(b * gridDim.x + s)) * DDIM + d] = acc;
}

// ---------------- k_reduce: summary[b,d] = sum_s part[b,s,d]
__global__ __launch_bounds__(256) void k_reduce(const float* __restrict__ part,
                                                float* __restrict__ out, int nsplit) {
    int i = blockIdx.x * 256 + threadIdx.x;
    int b = i >> 8, d = i & 255;
    float s = 0.f;
    for (int k = 0; k < nsplit; ++k) s += part[((size_t)(b * nsplit + k)) * DDIM + d];
    out[i] = s;
}

extern "C" void kernel_launch(void* const* d_in, const int* in_sizes, int n_in,
                              void* d_out, int out_size, void* d_ws, size_t ws_size,
                              hipStream_t stream) {
    const float* x     = (const float*)d_in[0];
    const float* gamma = (const float*)d_in[1];
    const float* beta  = (const float*)d_in[2];
    const float* W1    = (const float*)d_in[3];
    const float* b1    = (const float*)d_in[4];
    const float* W2    = (const float*)d_in[5];
    // d_in[6] = b2: softmax-invariant, unused.

    float* out     = (float*)d_out;
    float* summary = out;                       // B*D
    float* wts     = out + (size_t)BDIM * DDIM; // B*N (logits staged, then weights)

    // ws layout: c12 (512B) | ghi (32KB) | glo (32KB) | part (2MB)
    float*  c12 = (float*)d_ws;
    ushort* ghi = (ushort*)((char*)d_ws + 512);
    ushort* glo = ghi + 16384;
    float*  part = (float*)((char*)d_ws + 512 + 65536);
    size_t need_pack = 512 + 65536;

    const int NSPLIT = 8;
    size_t need_split = need_pack + (size_t)NSPLIT * BDIM * DDIM * sizeof(float);
    bool use_mfma = (ws_size >= need_pack);
    bool split    = (ws_size >= need_split);

    if (use_mfma) {
        hipLaunchKernelGGL(k_pre, dim3(64), dim3(256), 0, stream,
                           gamma, beta, W1, b1, c12, ghi, glo);
        hipLaunchKernelGGL(k_mfma, dim3(BDIM * NTOK / 64), dim3(256), 0, stream,
                           x, c12, ghi, glo, W2, wts);
    } else {
        hipLaunchKernelGGL(k_pre, dim3(1), dim3(256), 0, stream,
                           gamma, beta, W1, b1, c12, ghi, glo);
        hipLaunchKernelGGL(k_logits, dim3(BDIM * NTOK / 128), dim3(256), 0, stream,
                           x, gamma, W1, W2, c12, wts);
    }
    hipLaunchKernelGGL(k_softmax, dim3(BDIM), dim3(256), 0, stream, wts);
    if (split) {
        hipLaunchKernelGGL(k_partial, dim3(NSPLIT, BDIM), dim3(256), 0, stream,
                           x, wts, part, NTOK / NSPLIT);
        hipLaunchKernelGGL(k_reduce, dim3(BDIM * DDIM / 256), dim3(256), 0, stream,
                           part, summary, NSPLIT);
    } else {
        hipLaunchKernelGGL(k_partial, dim3(1, BDIM), dim3(256), 0, stream,
                           x, wts, summary, NTOK);
    }
}

// Round 6
// 108.037 us; speedup vs baseline: 1.9769x; 1.3172x over previous
//
#include <hip/hip_runtime.h>
#include <math.h>

#define DDIM 256
#define HDIM 64
#define NTOK 1024
#define BDIM 256
#define NCH  16      // chunks per batch (NTOK/64)

typedef __attribute__((ext_vector_type(8))) short short8;
typedef __attribute__((ext_vector_type(4))) float f32x4;

__device__ __forceinline__ ushort f2bf(float f) {   // RNE f32 -> bf16 bits
    uint u = __float_as_uint(f);
    return (ushort)((u + 0x7FFF + ((u >> 16) & 1)) >> 16);
}
__device__ __forceinline__ float bf2f(ushort b) {
    return __uint_as_float(((uint)b) << 16);
}

// ---------------- k_pre: c12 + split-bf16 pack of G = gamma ⊙ W1 in MFMA B-fragment order.
// B-frag (16x16x32): lane l holds B[k = (l>>4)*8 + j][n = l&15], j=0..7, contiguous 16B.
// ghi/glo[e], e = ((kt*4+nt)*64 + lane)*8 + j.   (validated R4/R5)
__global__ void k_pre(const float* __restrict__ gamma, const float* __restrict__ beta,
                      const float* __restrict__ W1, const float* __restrict__ b1,
                      float* __restrict__ c12, ushort* __restrict__ ghi,
                      ushort* __restrict__ glo) {
    int tid = threadIdx.x;
    if (blockIdx.x == 0 && tid < HDIM) {
        float s1 = 0.f, s2 = 0.f;
        for (int d = 0; d < DDIM; ++d) {
            float w = W1[d * HDIM + tid];
            s1 = fmaf(gamma[d], w, s1);
            s2 = fmaf(beta[d],  w, s2);
        }
        c12[tid]        = s1;
        c12[HDIM + tid] = s2 + b1[tid];
    }
    int e = blockIdx.x * 256 + tid;            // 64 blocks x 256 = 16384 entries
    int j    = e & 7;
    int lane = (e >> 3) & 63;
    int nt   = (e >> 9) & 3;
    int kt   = e >> 11;
    int k = kt * 32 + (lane >> 4) * 8 + j;
    int n = nt * 16 + (lane & 15);
    float g = gamma[k] * W1[k * HDIM + n];
    ushort hi = f2bf(g);
    ushort lo = f2bf(g - bf2f(hi));
    ghi[e] = hi;
    glo[e] = lo;
}

// ---------------- k_fused: LN-stats + split-bf16 MFMA logits + chunk-softmax +
// unnormalized weighted partial sum, all in one x pass. 64 tokens/block, 4 waves.
// Phase 1 = R5's k_mfma (validated). Phase 2 re-reads the L2-hot tile for S_c.
__global__ __launch_bounds__(256) void k_fused(
    const float* __restrict__ x, const float* __restrict__ c12,
    const ushort* __restrict__ ghi, const ushort* __restrict__ glo,
    const float* __restrict__ W2, float* __restrict__ logits,
    float* __restrict__ Sc, float2* __restrict__ ml) {
    __shared__ float  slog[64];
    __shared__ float4 Sw[4][64];
    __shared__ float  lsum[4];

    int tid = threadIdx.x, w = tid >> 6, lane = tid & 63;
    int m = lane & 15, kg = lane >> 4;
    size_t tok0 = (size_t)blockIdx.x * 64;          // block's 64 tokens
    size_t wtok = tok0 + (size_t)w * 16;            // wave's 16 tokens

    const float4*  rp  = reinterpret_cast<const float4*>(x + (wtok + m) * DDIM + kg * 8);
    const short8*  gph = reinterpret_cast<const short8*>(ghi);
    const short8*  gpl = reinterpret_cast<const short8*>(glo);

    f32x4 acc[4];
    #pragma unroll
    for (int nt = 0; nt < 4; ++nt) acc[nt] = (f32x4){0.f, 0.f, 0.f, 0.f};

    float s1 = 0.f, s2 = 0.f;

    #pragma unroll
    for (int kt = 0; kt < 8; ++kt) {
        float4 xa = rp[kt * 8];        // k = kt*32 + kg*8 + {0..3}
        float4 xb = rp[kt * 8 + 1];    // k = kt*32 + kg*8 + {4..7}

        s1 += ((xa.x + xa.y) + (xa.z + xa.w)) + ((xb.x + xb.y) + (xb.z + xb.w));
        s2 = fmaf(xa.x, xa.x, s2); s2 = fmaf(xa.y, xa.y, s2);
        s2 = fmaf(xa.z, xa.z, s2); s2 = fmaf(xa.w, xa.w, s2);
        s2 = fmaf(xb.x, xb.x, s2); s2 = fmaf(xb.y, xb.y, s2);
        s2 = fmaf(xb.z, xb.z, s2); s2 = fmaf(xb.w, xb.w, s2);

        uint u0 = __float_as_uint(xa.x), u1 = __float_as_uint(xa.y);
        uint u2 = __float_as_uint(xa.z), u3 = __float_as_uint(xa.w);
        uint u4 = __float_as_uint(xb.x), u5 = __float_as_uint(xb.y);
        uint u6 = __float_as_uint(xb.z), u7 = __float_as_uint(xb.w);

        union { uint4 u; short8 s; } Ah, Al;
        Ah.u.x = (u0 >> 16) | (u1 & 0xFFFF0000u);
        Ah.u.y = (u2 >> 16) | (u3 & 0xFFFF0000u);
        Ah.u.z = (u4 >> 16) | (u5 & 0xFFFF0000u);
        Ah.u.w = (u6 >> 16) | (u7 & 0xFFFF0000u);
        uint r0 = __float_as_uint(xa.x - __uint_as_float(u0 & 0xFFFF0000u));
        uint r1 = __float_as_uint(xa.y - __uint_as_float(u1 & 0xFFFF0000u));
        uint r2 = __float_as_uint(xa.z - __uint_as_float(u2 & 0xFFFF0000u));
        uint r3 = __float_as_uint(xa.w - __uint_as_float(u3 & 0xFFFF0000u));
        uint r4 = __float_as_uint(xb.x - __uint_as_float(u4 & 0xFFFF0000u));
        uint r5 = __float_as_uint(xb.y - __uint_as_float(u5 & 0xFFFF0000u));
        uint r6 = __float_as_uint(xb.z - __uint_as_float(u6 & 0xFFFF0000u));
        uint r7 = __float_as_uint(xb.w - __uint_as_float(u7 & 0xFFFF0000u));
        Al.u.x = (r0 >> 16) | (r1 & 0xFFFF0000u);
        Al.u.y = (r2 >> 16) | (r3 & 0xFFFF0000u);
        Al.u.z = (r4 >> 16) | (r5 & 0xFFFF0000u);
        Al.u.w = (r6 >> 16) | (r7 & 0xFFFF0000u);

        #pragma unroll
        for (int nt = 0; nt < 4; ++nt) {
            short8 bh = gph[(kt * 4 + nt) * 64 + lane];
            short8 bl = gpl[(kt * 4 + nt) * 64 + lane];
            acc[nt] = __builtin_amdgcn_mfma_f32_16x16x32_bf16(Ah.s, bh, acc[nt], 0, 0, 0);
            acc[nt] = __builtin_amdgcn_mfma_f32_16x16x32_bf16(Al.s, bh, acc[nt], 0, 0, 0);
            acc[nt] = __builtin_amdgcn_mfma_f32_16x16x32_bf16(Ah.s, bl, acc[nt], 0, 0, 0);
        }
    }

    // Exact fp32 row stats (lane's 64 elems; union over kg-groups = full row).
    s1 += __shfl_xor(s1, 16); s1 += __shfl_xor(s1, 32);
    s2 += __shfl_xor(s2, 16); s2 += __shfl_xor(s2, 32);
    float mu  = s1 * (1.f / DDIM);
    float var = fmaf(-mu, mu, s2 * (1.f / DDIM));
    float sv  = rsqrtf(var + 1e-5f);

    // Epilogue: LN fixup + GELU + W2 dot; logits -> LDS + global.
    float c1v[4], c2v[4], w2v[4];
    #pragma unroll
    for (int nt = 0; nt < 4; ++nt) {
        c1v[nt] = c12[nt * 16 + m];
        c2v[nt] = c12[HDIM + nt * 16 + m];
        w2v[nt] = W2[nt * 16 + m];
    }
    #pragma unroll
    for (int r = 0; r < 4; ++r) {
        int row = kg * 4 + r;
        float mur = __shfl(mu, row);
        float svr = __shfl(sv, row);
        float v = 0.f;
        #pragma unroll
        for (int nt = 0; nt < 4; ++nt) {
            float pre = fmaf(svr, fmaf(-mur, c1v[nt], acc[nt][r]), c2v[nt]);
            float g   = 0.5f * pre * (1.f + erff(pre * 0.70710678118654752f));
            v = fmaf(g, w2v[nt], v);
        }
        v += __shfl_xor(v, 1); v += __shfl_xor(v, 2);
        v += __shfl_xor(v, 4); v += __shfl_xor(v, 8);
        if (m == 0) {
            slog[w * 16 + row]  = v;
            logits[wtok + row]  = v;
        }
    }
    __syncthreads();

    // ---- Phase 2: chunk softmax + unnormalized weighted sum (tile is L1/L2-hot).
    const float4* sl4 = reinterpret_cast<const float4*>(slog);
    float mc = -1e30f;
    #pragma unroll
    for (int i = 0; i < 16; ++i) {
        float4 q = sl4[i];
        mc = fmaxf(mc, fmaxf(fmaxf(q.x, q.y), fmaxf(q.z, q.w)));
    }

    float4 a4 = {0.f, 0.f, 0.f, 0.f};
    float lw = 0.f;
    const float* xb0 = x + wtok * DDIM;
    #pragma unroll
    for (int r = 0; r < 16; ++r) {
        float p = __expf(slog[w * 16 + r] - mc);
        lw += p;
        float4 xv = *reinterpret_cast<const float4*>(xb0 + (size_t)r * DDIM + lane * 4);
        a4.x = fmaf(p, xv.x, a4.x); a4.y = fmaf(p, xv.y, a4.y);
        a4.z = fmaf(p, xv.z, a4.z); a4.w = fmaf(p, xv.w, a4.w);
    }
    Sw[w][lane] = a4;
    if (lane == 0) lsum[w] = lw;
    __syncthreads();

    if (w == 0) {
        float4 s0 = Sw[0][lane], q1 = Sw[1][lane], q2 = Sw[2][lane], q3 = Sw[3][lane];
        float4 S;
        S.x = (s0.x + q1.x) + (q2.x + q3.x);
        S.y = (s0.y + q1.y) + (q2.y + q3.y);
        S.z = (s0.z + q1.z) + (q2.z + q3.z);
        S.w = (s0.w + q1.w) + (q2.w + q3.w);
        reinterpret_cast<float4*>(Sc + (size_t)blockIdx.x * DDIM)[lane] = S;
        if (lane == 0)
            ml[blockIdx.x] = make_float2(mc, (lsum[0] + lsum[1]) + (lsum[2] + lsum[3]));
    }
}

// ---------------- k_combine: per batch, merge 16 chunks -> summary + weights.
// summary[b,d] = sum_c e^{m_c-M} Sc[c,d] / denom;  weights[n] = e^{logit_n - M}/denom.
__global__ __launch_bounds__(256) void k_combine(
    const float* __restrict__ Sc, const float2* __restrict__ ml,
    float* __restrict__ summary, float* __restrict__ wts) {
    int b = blockIdx.x, tid = threadIdx.x;

    float2 mlv[NCH];
    float M = -1e30f;
    #pragma unroll
    for (int c = 0; c < NCH; ++c) { mlv[c] = ml[b * NCH + c]; M = fmaxf(M, mlv[c].x); }
    float ex[NCH];
    float denom = 0.f;
    #pragma unroll
    for (int c = 0; c < NCH; ++c) {
        ex[c] = __expf(mlv[c].x - M);
        denom = fmaf(ex[c], mlv[c].y, denom);
    }
    float inv = 1.f / denom;

    float s = 0.f;
    #pragma unroll
    for (int c = 0; c < NCH; ++c)
        s = fmaf(ex[c], Sc[((size_t)b * NCH + c) * DDIM + tid], s);
    summary[(size_t)b * DDIM + tid] = s * inv;

    // weights: 4 tokens per thread, in-place over staged logits.
    float4* wp = reinterpret_cast<float4*>(wts + (size_t)b * NTOK) + tid;
    float4 lg = *wp;
    lg.x = __expf(lg.x - M) * inv;
    lg.y = __expf(lg.y - M) * inv;
    lg.z = __expf(lg.z - M) * inv;
    lg.w = __expf(lg.w - M) * inv;
    *wp = lg;
}

extern "C" void kernel_launch(void* const* d_in, const int* in_sizes, int n_in,
                              void* d_out, int out_size, void* d_ws, size_t ws_size,
                              hipStream_t stream) {
    const float* x     = (const float*)d_in[0];
    const float* gamma = (const float*)d_in[1];
    const float* beta  = (const float*)d_in[2];
    const float* W1    = (const float*)d_in[3];
    const float* b1    = (const float*)d_in[4];
    const float* W2    = (const float*)d_in[5];
    // d_in[6] = b2: softmax-invariant, unused.

    float* out     = (float*)d_out;
    float* summary = out;                       // B*D
    float* wts     = out + (size_t)BDIM * DDIM; // B*N (logits staged, then weights)

    // ws layout: c12 (512B) | ghi (32KB) | glo (32KB) | Sc (4MB) | ml (32KB)
    float*  c12 = (float*)d_ws;
    ushort* ghi = (ushort*)((char*)d_ws + 512);
    ushort* glo = ghi + 16384;
    float*  Sc  = (float*)((char*)d_ws + 512 + 65536);
    float2* ml  = (float2*)((char*)d_ws + 512 + 65536 +
                            (size_t)BDIM * NCH * DDIM * sizeof(float));

    hipLaunchKernelGGL(k_pre, dim3(64), dim3(256), 0, stream,
                       gamma, beta, W1, b1, c12, ghi, glo);
    hipLaunchKernelGGL(k_fused, dim3(BDIM * NCH), dim3(256), 0, stream,
                       x, c12, ghi, glo, W2, wts, Sc, ml);
    hipLaunchKernelGGL(k_combine, dim3(BDIM), dim3(256), 0, stream,
                       Sc, ml, summary, wts);
}